// Round 1
// baseline (7488.001 us; speedup 1.0000x reference)
//
#include <hip/hip_runtime.h>
#include <math.h>

#define T_LEN 256
#define B_SZ  64
#define IN_D  512
#define H_D   1024
#define G4    4096   // 4*H

typedef float  f32x4 __attribute__((ext_vector_type(4)));
typedef short  s16x8 __attribute__((ext_vector_type(8)));
typedef unsigned short u16;

// ---------- helpers ----------
__device__ __forceinline__ void gl_lds16(const void* g, void* l) {
  __builtin_amdgcn_global_load_lds(
      (const __attribute__((address_space(1))) unsigned int*)g,
      (__attribute__((address_space(3))) unsigned int*)l, 16, 0, 0);
}

__device__ __forceinline__ u16 f2bf(float f) {
  union { float f; unsigned u; } v; v.f = f;
  unsigned x = v.u;
  unsigned r = (x + 0x7fffu + ((x >> 16) & 1u)) >> 16;  // RNE
  return (u16)r;
}
__device__ __forceinline__ float bf2f(u16 b) {
  union { unsigned u; float f; } v; v.u = ((unsigned)b) << 16;
  return v.f;
}
__device__ __forceinline__ float sigm(float x) {
  return 1.0f / (1.0f + __expf(-x));
}

// ---------- fp32 -> bf16 convert ----------
__global__ void cvt_f32_bf16(const float* __restrict__ src, u16* __restrict__ dst, int n) {
  int i = blockIdx.x * blockDim.x + threadIdx.x;
  int stride = gridDim.x * blockDim.x;
  for (; i < n; i += stride) dst[i] = f2bf(src[i]);
}

// ---------- generic bf16 GEMM: C[M,N] = A[M,K] * B[N,K]^T (+epilogue) ----------
// 128x128 block tile, BK=64, 4 waves (2x2), 16x16x32 MFMA, global_load_lds staging
// with XOR-row chunk swizzle for conflict-free ds_read_b128 fragment loads.
// EPI 0: out bf16 = acc + bias[col] + (row<64 ? img[row][col&1023] : 0)   (xproj)
// EPI 1: out f32  = acc + bias[col]                                       (logits)
template<int KD, int EPI>
__launch_bounds__(256)
__global__ void gemm_bt(const u16* __restrict__ A, const u16* __restrict__ Bm,
                        const float* __restrict__ bias, const float* __restrict__ img,
                        u16* __restrict__ Cb, float* __restrict__ Cf, int Ncols) {
  __shared__ u16 sA[128 * 64];
  __shared__ u16 sB[128 * 64];
  const int tid  = threadIdx.x;
  const int wave = tid >> 6, lane = tid & 63;
  const int wm = wave >> 1, wn = wave & 1;
  const int mBase = blockIdx.y * 128;
  const int nBase = blockIdx.x * 128;

  f32x4 acc[4][4] = {};

  for (int k0 = 0; k0 < KD; k0 += 64) {
    // stage A,B tiles: slot s = it*256+tid holds 16B; row = s>>3, chunk = s&7,
    // global chunk fetched = chunk ^ (row&7)  (swizzle on the global side)
#pragma unroll
    for (int it = 0; it < 4; ++it) {
      int s = it * 256 + tid;
      int row = s >> 3, c = s & 7;
      int gc = c ^ (row & 7);
      const u16* ga = A  + (size_t)(mBase + row) * KD + k0 + gc * 8;
      const u16* gb = Bm + (size_t)(nBase + row) * KD + k0 + gc * 8;
      gl_lds16(ga, &sA[(it * 256 + wave * 64) * 8]);
      gl_lds16(gb, &sB[(it * 256 + wave * 64) * 8]);
    }
    __syncthreads();

    const int q = lane >> 4, rl = lane & 15;
#pragma unroll
    for (int ks = 0; ks < 64; ks += 32) {
      s16x8 af[4], bfr[4];
      int gcb = (ks >> 3) + q;   // global k-chunk 0..7
#pragma unroll
      for (int i = 0; i < 4; ++i) {
        int rowA = wm * 64 + i * 16 + rl;
        af[i]  = *(const s16x8*)&sA[rowA * 64 + (gcb ^ (rowA & 7)) * 8];
        int rowB = wn * 64 + i * 16 + rl;
        bfr[i] = *(const s16x8*)&sB[rowB * 64 + (gcb ^ (rowB & 7)) * 8];
      }
#pragma unroll
      for (int i = 0; i < 4; ++i)
#pragma unroll
        for (int j = 0; j < 4; ++j)
          acc[i][j] = __builtin_amdgcn_mfma_f32_16x16x32_bf16(af[i], bfr[j], acc[i][j], 0, 0, 0);
    }
    __syncthreads();
  }

  // epilogue: C/D layout col=lane&15, row=(lane>>4)*4+r
#pragma unroll
  for (int i = 0; i < 4; ++i) {
    int rbase = mBase + wm * 64 + i * 16 + ((lane >> 4) << 2);
#pragma unroll
    for (int j = 0; j < 4; ++j) {
      int col = nBase + wn * 64 + j * 16 + (lane & 15);
      float bc = bias[col];
#pragma unroll
      for (int r = 0; r < 4; ++r) {
        int row = rbase + r;
        float v = acc[i][j][r] + bc;
        if (EPI == 0) {
          if (row < B_SZ) v += img[row * H_D + (col & (H_D - 1))];
          Cb[(size_t)row * Ncols + col] = f2bf(v);
        } else {
          Cf[(size_t)row * Ncols + col] = v;
        }
      }
    }
  }
}

// ---------- persistent LSTM recurrence ----------
// grid = 256 blocks = 4 batch-groups x 64 column-slices; block = 256 thr (4 waves).
// WG (grp,wg): batches [grp*16,grp*16+16), h-columns [wg*16,wg*16+16).
// Whh rows {g*1024 + wg*16 + c : g in 0..3, c in 0..15} resident in LDS (padded).
// c-state: 1 fp32 register per thread. h round-trips via global hs[] (bf16) with
// per-group flag handshake (device-scope atomics) instead of a grid barrier.
#define WPAD 1032   // 1024 + 8 bf16 pad (16B) -> B-frag reads 2-way (free)
__launch_bounds__(256, 1)
__global__ void lstm_rec(const u16* __restrict__ WhhB, const u16* __restrict__ xproj,
                         const float* __restrict__ bhh, u16* __restrict__ hs,
                         int* __restrict__ flags) {
  __shared__ u16  sW[64 * WPAD];     // 132 KB, persistent Whh slice
  __shared__ u16  sH[16 * 512];      // 16 KB, h K-chunk
  __shared__ float sG[4][16][16];    // 4 KB, gate exchange

  const int tid  = threadIdx.x;
  const int wave = tid >> 6, lane = tid & 63;
  const int grp = blockIdx.x >> 6;       // 0..3
  const int wg  = blockIdx.x & 63;       // 0..63
  const int bBase = grp * 16;
  const int colBase = wg * 16;

  // load Whh slice (64 rows x 1024) into padded LDS
  for (int it = 0; it < 32; ++it) {
    int s = it * 256 + tid;              // 16B chunk id, 8192 total
    int n = s >> 7, c = s & 127;         // row 0..63, chunk 0..127
    int grow = (n >> 4) * H_D + colBase + (n & 15);
    s16x8 v = *(const s16x8*)(WhhB + (size_t)grow * H_D + c * 8);
    *(s16x8*)&sW[n * WPAD + c * 8] = v;
  }
  __syncthreads();

  float cst = 0.f;
  const int ub = tid >> 4, uc = tid & 15;     // local (batch, col) for cell update
  const int gb = bBase + ub;
  const int gcol = colBase + uc;
  const float bh_i = bhh[0 * H_D + gcol], bh_f = bhh[1 * H_D + gcol];
  const float bh_g = bhh[2 * H_D + gcol], bh_o = bhh[3 * H_D + gcol];

  for (int t = 0; t < T_LEN; ++t) {
    f32x4 acc = {0.f, 0.f, 0.f, 0.f};
    if (t > 0) {
      // wait for all 64 producers of this group's h[t-1]
      if (tid < 64) {
        const int* fp = flags + (t - 1) * 256 + grp * 64 + tid;
        while (__hip_atomic_load(fp, __ATOMIC_ACQUIRE, __HIP_MEMORY_SCOPE_AGENT) == 0)
          __builtin_amdgcn_s_sleep(1);
      }
      __syncthreads();
      const u16* hprev = hs + (size_t)(t - 1) * B_SZ * H_D;
#pragma unroll
      for (int half = 0; half < 2; ++half) {
        // stage h chunk [16 batches][512 k], swizzled
#pragma unroll
        for (int it = 0; it < 4; ++it) {
          int s = it * 256 + tid;
          int row = s >> 6, c = s & 63;
          int gc = c ^ (row & 7);
          gl_lds16(hprev + (size_t)(bBase + row) * H_D + half * 512 + gc * 8,
                   &sH[(it * 256 + wave * 64) * 8]);
        }
        __syncthreads();
        const int q = lane >> 4, rl = lane & 15;
#pragma unroll
        for (int ks = 0; ks < 512; ks += 32) {
          int gc = (ks >> 3) + q;
          s16x8 afr = *(const s16x8*)&sH[rl * 512 + (gc ^ (rl & 7)) * 8];
          s16x8 bfr = *(const s16x8*)&sW[(wave * 16 + rl) * WPAD + half * 512 + ks + q * 8];
          acc = __builtin_amdgcn_mfma_f32_16x16x32_bf16(afr, bfr, acc, 0, 0, 0);
        }
        __syncthreads();
      }
      // wave g owns gate g tile: rows=batch, cols=h-col
#pragma unroll
      for (int r = 0; r < 4; ++r)
        sG[wave][(lane >> 4) * 4 + r][lane & 15] = acc[r];
      __syncthreads();
    }

    // cell update: one (batch,col) per thread
    const u16* xp = xproj + ((size_t)t * B_SZ + gb) * G4;
    float gi_ = bf2f(xp[0 * H_D + gcol]) + bh_i;
    float gf_ = bf2f(xp[1 * H_D + gcol]) + bh_f;
    float gg_ = bf2f(xp[2 * H_D + gcol]) + bh_g;
    float go_ = bf2f(xp[3 * H_D + gcol]) + bh_o;
    if (t > 0) {
      gi_ += sG[0][ub][uc]; gf_ += sG[1][ub][uc];
      gg_ += sG[2][ub][uc]; go_ += sG[3][ub][uc];
    }
    cst = sigm(gf_) * cst + sigm(gi_) * tanhf(gg_);
    float h = sigm(go_) * tanhf(cst);
    hs[((size_t)t * B_SZ + gb) * H_D + gcol] = f2bf(h);

    __threadfence();        // agent-scope release of hs writes
    __syncthreads();        // all threads done (also protects sG reuse)
    if (tid == 0)
      __hip_atomic_store(&flags[t * 256 + grp * 64 + wg], 1,
                         __ATOMIC_RELEASE, __HIP_MEMORY_SCOPE_AGENT);
  }
}

// ---------- in-place log_softmax over rows of 512 ----------
__launch_bounds__(256)
__global__ void logsoftmax_rows(float* __restrict__ out) {
  __shared__ float red[8];
  float* p = out + (size_t)blockIdx.x * IN_D;
  const int tid = threadIdx.x;
  float v0 = p[tid], v1 = p[tid + 256];
  float m = fmaxf(v0, v1);
#pragma unroll
  for (int off = 32; off > 0; off >>= 1) m = fmaxf(m, __shfl_down(m, off));
  if ((tid & 63) == 0) red[tid >> 6] = m;
  __syncthreads();
  m = fmaxf(fmaxf(red[0], red[1]), fmaxf(red[2], red[3]));
  float e = __expf(v0 - m) + __expf(v1 - m);
#pragma unroll
  for (int off = 32; off > 0; off >>= 1) e += __shfl_down(e, off);
  if ((tid & 63) == 0) red[4 + (tid >> 6)] = e;
  __syncthreads();
  float ls = m + logf(red[4] + red[5] + red[6] + red[7]);
  p[tid] = v0 - ls;
  p[tid + 256] = v1 - ls;
}

// ---------- launch ----------
extern "C" void kernel_launch(void* const* d_in, const int* in_sizes, int n_in,
                              void* d_out, int out_size, void* d_ws, size_t ws_size,
                              hipStream_t stream) {
  const float* inp  = (const float*)d_in[0];
  const float* img  = (const float*)d_in[1];
  const float* Wxh  = (const float*)d_in[2];
  const float* bxh  = (const float*)d_in[3];
  const float* Whh  = (const float*)d_in[4];
  const float* bhh  = (const float*)d_in[5];
  const float* Wout = (const float*)d_in[6];
  const float* bout = (const float*)d_in[7];
  float* out = (float*)d_out;

  char* ws = (char*)d_ws;
  u16* inpB   = (u16*)(ws);                    // 16 MB  (256*64*512)
  u16* WxhB   = (u16*)(ws + 16777216);         // 4 MB   (4096*512)
  u16* WhhB   = (u16*)(ws + 20971520);         // 8 MB   (4096*1024)
  u16* WoutB  = (u16*)(ws + 29360128);         // 1 MB   (512*1024)
  u16* xprojB = (u16*)(ws + 30408704);         // 128 MB (16384*4096)
  u16* hsB    = (u16*)(ws + 164626432);        // 32 MB  (256*64*1024)
  int* flags  = (int*)(ws + 198180864);        // 256 KB (256*256)

  cvt_f32_bf16<<<2048, 256, 0, stream>>>(inp,  inpB,  T_LEN * B_SZ * IN_D);
  cvt_f32_bf16<<<2048, 256, 0, stream>>>(Wxh,  WxhB,  G4 * IN_D);
  cvt_f32_bf16<<<2048, 256, 0, stream>>>(Whh,  WhhB,  G4 * H_D);
  cvt_f32_bf16<<<2048, 256, 0, stream>>>(Wout, WoutB, IN_D * H_D);
  hipMemsetAsync(flags, 0, T_LEN * 256 * sizeof(int), stream);

  // xproj = inp@Wxh^T + bxh (+ img4 at t=0), bf16 out
  gemm_bt<IN_D, 0><<<dim3(G4 / 128, 16384 / 128), 256, 0, stream>>>(
      inpB, WxhB, bxh, img, xprojB, nullptr, G4);

  lstm_rec<<<256, 256, 0, stream>>>(WhhB, xprojB, bhh, hsB, flags);

  // logits = hs@Wout^T + bout, f32 into d_out
  gemm_bt<H_D, 1><<<dim3(IN_D / 128, 16384 / 128), 256, 0, stream>>>(
      hsB, WoutB, bout, nullptr, nullptr, out, IN_D);

  logsoftmax_rows<<<16384, 256, 0, stream>>>(out);
}

// Round 2
// 1195.992 us; speedup vs baseline: 6.2609x; 6.2609x over previous
//
#include <hip/hip_runtime.h>
#include <math.h>

#define T_LEN 256
#define B_SZ  64
#define IN_D  512
#define H_D   1024
#define G4    4096   // 4*H

typedef float  f32x4 __attribute__((ext_vector_type(4)));
typedef short  s16x8 __attribute__((ext_vector_type(8)));
typedef unsigned short u16;
typedef unsigned int   u32;

// ---------- helpers ----------
__device__ __forceinline__ void gl_lds16(const void* g, void* l) {
  __builtin_amdgcn_global_load_lds(
      (const __attribute__((address_space(1))) unsigned int*)g,
      (__attribute__((address_space(3))) unsigned int*)l, 16, 0, 0);
}

__device__ __forceinline__ u16 f2bf(float f) {
  union { float f; unsigned u; } v; v.f = f;
  unsigned x = v.u;
  unsigned r = (x + 0x7fffu + ((x >> 16) & 1u)) >> 16;  // RNE
  return (u16)r;
}
__device__ __forceinline__ float bf2f(u16 b) {
  union { unsigned u; float f; } v; v.u = ((unsigned)b) << 16;
  return v.f;
}
__device__ __forceinline__ float sigm(float x) {
  return 1.0f / (1.0f + __expf(-x));
}

// ---------- fp32 -> bf16 convert ----------
__global__ void cvt_f32_bf16(const float* __restrict__ src, u16* __restrict__ dst, int n) {
  int i = blockIdx.x * blockDim.x + threadIdx.x;
  int stride = gridDim.x * blockDim.x;
  for (; i < n; i += stride) dst[i] = f2bf(src[i]);
}

// ---------- generic bf16 GEMM: C[M,N] = A[M,K] * B[N,K]^T (+epilogue) ----------
// 128x128 block tile, BK=64, 4 waves (2x2), 16x16x32 MFMA, global_load_lds staging
// with XOR-row chunk swizzle for conflict-free ds_read_b128 fragment loads.
// EPI 0: out bf16 = acc + bias[col] + (row<64 ? img[row][col&1023] : 0)   (xproj)
// EPI 1: out f32  = acc + bias[col]                                       (logits)
template<int KD, int EPI>
__launch_bounds__(256)
__global__ void gemm_bt(const u16* __restrict__ A, const u16* __restrict__ Bm,
                        const float* __restrict__ bias, const float* __restrict__ img,
                        u16* __restrict__ Cb, float* __restrict__ Cf, int Ncols) {
  __shared__ u16 sA[128 * 64];
  __shared__ u16 sB[128 * 64];
  const int tid  = threadIdx.x;
  const int wave = tid >> 6, lane = tid & 63;
  const int wm = wave >> 1, wn = wave & 1;
  const int mBase = blockIdx.y * 128;
  const int nBase = blockIdx.x * 128;

  f32x4 acc[4][4] = {};

  for (int k0 = 0; k0 < KD; k0 += 64) {
#pragma unroll
    for (int it = 0; it < 4; ++it) {
      int s = it * 256 + tid;
      int row = s >> 3, c = s & 7;
      int gc = c ^ (row & 7);
      const u16* ga = A  + (size_t)(mBase + row) * KD + k0 + gc * 8;
      const u16* gb = Bm + (size_t)(nBase + row) * KD + k0 + gc * 8;
      gl_lds16(ga, &sA[(it * 256 + wave * 64) * 8]);
      gl_lds16(gb, &sB[(it * 256 + wave * 64) * 8]);
    }
    __syncthreads();

    const int q = lane >> 4, rl = lane & 15;
#pragma unroll
    for (int ks = 0; ks < 64; ks += 32) {
      s16x8 af[4], bfr[4];
      int gcb = (ks >> 3) + q;
#pragma unroll
      for (int i = 0; i < 4; ++i) {
        int rowA = wm * 64 + i * 16 + rl;
        af[i]  = *(const s16x8*)&sA[rowA * 64 + (gcb ^ (rowA & 7)) * 8];
        int rowB = wn * 64 + i * 16 + rl;
        bfr[i] = *(const s16x8*)&sB[rowB * 64 + (gcb ^ (rowB & 7)) * 8];
      }
#pragma unroll
      for (int i = 0; i < 4; ++i)
#pragma unroll
        for (int j = 0; j < 4; ++j)
          acc[i][j] = __builtin_amdgcn_mfma_f32_16x16x32_bf16(af[i], bfr[j], acc[i][j], 0, 0, 0);
    }
    __syncthreads();
  }

  // epilogue: C/D layout col=lane&15, row=(lane>>4)*4+r
#pragma unroll
  for (int i = 0; i < 4; ++i) {
    int rbase = mBase + wm * 64 + i * 16 + ((lane >> 4) << 2);
#pragma unroll
    for (int j = 0; j < 4; ++j) {
      int col = nBase + wn * 64 + j * 16 + (lane & 15);
      float bc = bias[col];
#pragma unroll
      for (int r = 0; r < 4; ++r) {
        int row = rbase + r;
        float v = acc[i][j][r] + bc;
        if (EPI == 0) {
          if (row < B_SZ) v += img[row * H_D + (col & (H_D - 1))];
          Cb[(size_t)row * Ncols + col] = f2bf(v);
        } else {
          Cf[(size_t)row * Ncols + col] = v;
        }
      }
    }
  }
}

// ---------- persistent LSTM recurrence ----------
// grid = 256 blocks = 4 batch-groups x 64 column-slices; block = 256 thr (4 waves).
// WG (grp,wg): batches [grp*16,+16), h-columns [wg*16,+16). Whh slice resident in
// LDS. Cross-WG h transport: relaxed AGENT-scope atomics only (global_* sc1 —
// write-through/read-through at the LLC, NO buffer_wbl2 / buffer_inv — the
// round-1 __threadfence() L2-writeback+invalidate per step was the 29 us/step).
// Ordering: per-wave s_waitcnt(0) after h stores -> __syncthreads -> flag store;
// consumers spin on relaxed flag loads then issue relaxed h loads (LLC-coherent).
#define WPAD 1032   // 1024 + 8 bf16 pad -> B-frag ds_reads 2-way (free)
__launch_bounds__(256, 1)
__global__ void lstm_rec(const u16* __restrict__ WhhB, const u16* __restrict__ xproj,
                         const float* __restrict__ bhh, u32* __restrict__ hs32,
                         int* __restrict__ flags) {
  __shared__ u16  sW[64 * WPAD];     // 132 KB, persistent Whh slice
  __shared__ u16  sH[16 * 512];      // 16 KB, h half-K tile (swizzled)
  __shared__ float sG[4][16][16];    // 4 KB, gate exchange

  const int tid  = threadIdx.x;
  const int wave = tid >> 6, lane = tid & 63;
  const int grp = blockIdx.x >> 6;       // 0..3
  const int wg  = blockIdx.x & 63;       // 0..63
  const int bBase = grp * 16;
  const int colBase = wg * 16;

  // load Whh slice (64 rows x 1024) into padded LDS
  for (int it = 0; it < 32; ++it) {
    int s = it * 256 + tid;              // 16B chunk id, 8192 total
    int n = s >> 7, c = s & 127;         // row 0..63, chunk 0..127
    int grow = (n >> 4) * H_D + colBase + (n & 15);
    s16x8 v = *(const s16x8*)(WhhB + (size_t)grow * H_D + c * 8);
    *(s16x8*)&sW[n * WPAD + c * 8] = v;
  }
  __syncthreads();

  float cst = 0.f;
  const int ub = tid >> 4, uc = tid & 15;     // local (batch, col) for cell update
  const int gb = bBase + ub;
  const int gcol = colBase + uc;
  const float bh_i = bhh[0 * H_D + gcol], bh_f = bhh[1 * H_D + gcol];
  const float bh_g = bhh[2 * H_D + gcol], bh_o = bhh[3 * H_D + gcol];
  const int q = lane >> 4, rl = lane & 15;

  for (int t = 0; t < T_LEN; ++t) {
    // issue xproj loads early: latency hides under the flag wait
    const u16* xp = xproj + ((size_t)t * B_SZ + gb) * G4;
    float gi_ = bf2f(xp[0 * H_D + gcol]) + bh_i;
    float gf_ = bf2f(xp[1 * H_D + gcol]) + bh_f;
    float gg_ = bf2f(xp[2 * H_D + gcol]) + bh_g;
    float go_ = bf2f(xp[3 * H_D + gcol]) + bh_o;

    if (t > 0) {
      // wait for all 64 producers of this group's h[t-1]
      if (tid < 64) {
        const int* fp = flags + (t - 1) * 256 + grp * 64 + tid;
        while (__hip_atomic_load(fp, __ATOMIC_RELAXED, __HIP_MEMORY_SCOPE_AGENT) == 0)
          __builtin_amdgcn_s_sleep(1);
      }
      __syncthreads();

      // bulk-load h[t-1] for this group's 16 batches: 8192 pair-dwords, 32/thread.
      // j even -> K-half 0, j odd -> K-half 1; row = j>>1, within-half pair = tid.
      u32 v[32];
      const u32* hp = hs32 + (size_t)(t - 1) * B_SZ * 512 + (size_t)bBase * 512;
#pragma unroll
      for (int j = 0; j < 32; ++j) {
        int d = j * 256 + tid;               // row = d>>9, pair = d&511
        v[j] = __hip_atomic_load(&hp[(d >> 9) * 512 + (d & 511)],
                                 __ATOMIC_RELAXED, __HIP_MEMORY_SCOPE_AGENT);
      }

      f32x4 acc = {0.f, 0.f, 0.f, 0.f};
#pragma unroll
      for (int half = 0; half < 2; ++half) {
        // scatter this half into swizzled sH: cols 2*tid,2*tid+1 of row r
        int chunk = tid >> 2;                 // within-half 8-elem chunk
        int off = (tid & 3) * 2;
#pragma unroll
        for (int r = 0; r < 16; ++r)
          *(u32*)&sH[r * 512 + ((chunk ^ (r & 7)) * 8 + off)] = v[2 * r + half];
        __syncthreads();
#pragma unroll
        for (int ks = 0; ks < 512; ks += 32) {
          int gc = (ks >> 3) + q;
          s16x8 afr = *(const s16x8*)&sH[rl * 512 + ((gc ^ (rl & 7)) & 63) * 8];
          s16x8 bfr = *(const s16x8*)&sW[(wave * 16 + rl) * WPAD + half * 512 + ks + q * 8];
          acc = __builtin_amdgcn_mfma_f32_16x16x32_bf16(afr, bfr, acc, 0, 0, 0);
        }
        __syncthreads();
      }
      // wave g owns gate g tile: rows=batch, cols=h-col
#pragma unroll
      for (int r = 0; r < 4; ++r)
        sG[wave][(lane >> 4) * 4 + r][lane & 15] = acc[r];
      __syncthreads();
      gi_ += sG[0][ub][uc]; gf_ += sG[1][ub][uc];
      gg_ += sG[2][ub][uc]; go_ += sG[3][ub][uc];
      __syncthreads();   // sG consumed before next-step reuse
    }

    // cell update: one (batch,col) per thread
    cst = sigm(gf_) * cst + sigm(gi_) * tanhf(gg_);
    float h = sigm(go_) * tanhf(cst);
    u32 bits = f2bf(h);
    u32 partner = (u32)__shfl_xor((int)bits, 1);
    if ((tid & 1) == 0) {
      // pair-dword (cols gcol, gcol+1), write-through to LLC
      __hip_atomic_store(&hs32[((size_t)t * B_SZ + gb) * 512 + (gcol >> 1)],
                         bits | (partner << 16),
                         __ATOMIC_RELAXED, __HIP_MEMORY_SCOPE_AGENT);
    }
    __builtin_amdgcn_s_waitcnt(0);   // per-wave: h stores acked at LLC
    __syncthreads();                 // all 4 waves drained
    if (tid == 0)
      __hip_atomic_store(&flags[t * 256 + grp * 64 + wg], 1,
                         __ATOMIC_RELAXED, __HIP_MEMORY_SCOPE_AGENT);
  }
}

// ---------- in-place log_softmax over rows of 512 ----------
__launch_bounds__(256)
__global__ void logsoftmax_rows(float* __restrict__ out) {
  __shared__ float red[8];
  float* p = out + (size_t)blockIdx.x * IN_D;
  const int tid = threadIdx.x;
  float v0 = p[tid], v1 = p[tid + 256];
  float m = fmaxf(v0, v1);
#pragma unroll
  for (int off = 32; off > 0; off >>= 1) m = fmaxf(m, __shfl_down(m, off));
  if ((tid & 63) == 0) red[tid >> 6] = m;
  __syncthreads();
  m = fmaxf(fmaxf(red[0], red[1]), fmaxf(red[2], red[3]));
  float e = __expf(v0 - m) + __expf(v1 - m);
#pragma unroll
  for (int off = 32; off > 0; off >>= 1) e += __shfl_down(e, off);
  if ((tid & 63) == 0) red[4 + (tid >> 6)] = e;
  __syncthreads();
  float ls = m + logf(red[4] + red[5] + red[6] + red[7]);
  p[tid] = v0 - ls;
  p[tid + 256] = v1 - ls;
}

// ---------- launch ----------
extern "C" void kernel_launch(void* const* d_in, const int* in_sizes, int n_in,
                              void* d_out, int out_size, void* d_ws, size_t ws_size,
                              hipStream_t stream) {
  const float* inp  = (const float*)d_in[0];
  const float* img  = (const float*)d_in[1];
  const float* Wxh  = (const float*)d_in[2];
  const float* bxh  = (const float*)d_in[3];
  const float* Whh  = (const float*)d_in[4];
  const float* bhh  = (const float*)d_in[5];
  const float* Wout = (const float*)d_in[6];
  const float* bout = (const float*)d_in[7];
  float* out = (float*)d_out;

  char* ws = (char*)d_ws;
  u16* inpB   = (u16*)(ws);                    // 16 MB  (256*64*512)
  u16* WxhB   = (u16*)(ws + 16777216);         // 4 MB   (4096*512)
  u16* WhhB   = (u16*)(ws + 20971520);         // 8 MB   (4096*1024)
  u16* WoutB  = (u16*)(ws + 29360128);         // 1 MB   (512*1024)
  u16* xprojB = (u16*)(ws + 30408704);         // 128 MB (16384*4096)
  u16* hsB    = (u16*)(ws + 164626432);        // 32 MB  (256*64*1024)
  int* flags  = (int*)(ws + 198180864);        // 256 KB (256*256)

  cvt_f32_bf16<<<2048, 256, 0, stream>>>(inp,  inpB,  T_LEN * B_SZ * IN_D);
  cvt_f32_bf16<<<2048, 256, 0, stream>>>(Wxh,  WxhB,  G4 * IN_D);
  cvt_f32_bf16<<<2048, 256, 0, stream>>>(Whh,  WhhB,  G4 * H_D);
  cvt_f32_bf16<<<2048, 256, 0, stream>>>(Wout, WoutB, IN_D * H_D);
  hipMemsetAsync(flags, 0, T_LEN * 256 * sizeof(int), stream);

  // xproj = inp@Wxh^T + bxh (+ img4 at t=0), bf16 out
  gemm_bt<IN_D, 0><<<dim3(G4 / 128, 16384 / 128), 256, 0, stream>>>(
      inpB, WxhB, bxh, img, xprojB, nullptr, G4);

  lstm_rec<<<256, 256, 0, stream>>>(WhhB, xprojB, bhh, (u32*)hsB, flags);

  // logits = hs@Wout^T + bout, f32 into d_out
  gemm_bt<H_D, 1><<<dim3(IN_D / 128, 16384 / 128), 256, 0, stream>>>(
      hsB, WoutB, bout, nullptr, nullptr, out, IN_D);

  logsoftmax_rows<<<16384, 256, 0, stream>>>(out);
}